// Round 14
// baseline (190.473 us; speedup 1.0000x reference)
//
#include <hip/hip_runtime.h>

typedef unsigned char u8;
typedef float f32x4 __attribute__((ext_vector_type(4)));
typedef unsigned long ulx2 __attribute__((ext_vector_type(2)));
typedef unsigned int uix2 __attribute__((ext_vector_type(2)));

#define DIM 512
#define EPSV 1e-6f
#define MARGIN 0.2f
#define DEPS2 (512.0f * 1e-6f * 1e-6f)
#define BK 64
#define NSLICE (DIM / BK)   // 8
#define RING 3
#define NTILES 2080

#define AS1 __attribute__((address_space(1)))
#define AS3 __attribute__((address_space(3)))

// ---------------- Kernel 1: per-row stats + fp8 e4m3 convert (k-permuted) ----------------
// Layout per row (512 B): k-block kb (64 elems), granule j (16 B) at byte
// kb*64 + j*16 = fp8[kb*64 + j*8 ..+7] (lo 8B) || fp8[kb*64 + 32 + j*8 ..+7] (hi 8B)
// -- one b128 LDS read yields BOTH K=32 MFMA frags (r13-verified).
__global__ __launch_bounds__(256) void prep_kernel(
        const float* __restrict__ A, const float* __restrict__ P,
        u8* __restrict__ Aq, float* __restrict__ alpha,
        float* __restrict__ beta, float* __restrict__ dap,
        unsigned int* __restrict__ dan2, unsigned int* __restrict__ cnt, int N) {
    int row = blockIdx.x * 4 + (threadIdx.x >> 6);
    int lane = threadIdx.x & 63;
    if (row >= N) return;
    const float* a = A + (size_t)row * DIM + lane * 8;
    const float* p = P + (size_t)row * DIM + lane * 8;
    float4 a0 = *(const float4*)(a);
    float4 a1 = *(const float4*)(a + 4);
    float4 p0 = *(const float4*)(p);
    float4 p1 = *(const float4*)(p + 4);
    float av[8] = {a0.x, a0.y, a0.z, a0.w, a1.x, a1.y, a1.z, a1.w};
    float pv[8] = {p0.x, p0.y, p0.z, p0.w, p1.x, p1.y, p1.z, p1.w};
    float sq = 0.f, s = 0.f, dp = 0.f;
    #pragma unroll
    for (int e = 0; e < 8; ++e) {
        float x = av[e];
        sq = fmaf(x, x, sq);
        s += x;
        float d = x - pv[e] + EPSV;
        dp = fmaf(d, d, dp);
    }
    unsigned w0 = __builtin_amdgcn_cvt_pk_fp8_f32(av[0], av[1], 0, false);
    w0 = __builtin_amdgcn_cvt_pk_fp8_f32(av[2], av[3], w0, true);
    unsigned w1 = __builtin_amdgcn_cvt_pk_fp8_f32(av[4], av[5], 0, false);
    w1 = __builtin_amdgcn_cvt_pk_fp8_f32(av[6], av[7], w1, true);
    int kb = lane >> 3, c = lane & 7;
    int dst = kb * 64 + (c & 3) * 16 + (c >> 2) * 8;
    uix2 w = {w0, w1};
    *reinterpret_cast<uix2*>(Aq + (size_t)row * DIM + dst) = w;

    #pragma unroll
    for (int mask = 32; mask; mask >>= 1) {
        sq += __shfl_xor(sq, mask, 64);
        s  += __shfl_xor(s,  mask, 64);
        dp += __shfl_xor(dp, mask, 64);
    }
    if (lane == 0) {
        alpha[row] = fmaf(2.0f * EPSV, s, sq);
        beta[row]  = fmaf(-2.0f * EPSV, s, sq);
        dap[row]   = sqrtf(dp);
        dan2[row]  = 0x7f800000u;   // +inf
        if (row == 0) *cnt = 0u;    // zero completion counter each call
    }
}

// ---------------- Kernel 2: 128x128 triangular ring-3 fp8 Gram + min + fused finalize ----
// r11 chassis (verified geometry/epilogue/staging) x r13 fp8 pipeline (verified):
// 4 waves (2x2), per-wave 64x64 = acc[4][4]; LDS ring-3 x {A[128],B[128]} rows
// of 64 B with granule rotation (0 conflicts); counted vmcnt(4)/slice; 48 KB
// -> 3 blocks/CU. Tail fix: 2080 tiles / 768 slots = 2.71 rounds (vs 2.06/512).
// Last-finishing block performs the loss reduction (saves a kernel + gap).
__global__ __launch_bounds__(256, 4) void gemm_min_kernel(
        const u8* __restrict__ Aq, const float* __restrict__ alpha,
        const float* __restrict__ beta, unsigned int* __restrict__ dan2,
        const float* __restrict__ dap, unsigned int* __restrict__ cnt,
        float* __restrict__ out, int N) {

    __shared__ u8 lds[RING][16384];   // 48 KiB: per slot A=8192 B, B=8192 B

    // XCD-chunked bijective swizzle: 2080 = 8 * 260
    int orig = blockIdx.x;
    int b = (orig & 7) * 260 + (orig >> 3);

    // triangular decode b -> (it, jt), it <= jt
    int jt = (int)((sqrtf(8.0f * (float)b + 1.0f) - 1.0f) * 0.5f);
    while ((jt + 1) * (jt + 2) / 2 <= b) ++jt;
    while (jt * (jt + 1) / 2 > b) --jt;
    int it = b - jt * (jt + 1) / 2;
    bool diag = (it == jt);
    int ibase = it << 7, jbase = jt << 7;

    int tid = threadIdx.x;
    int wave = tid >> 6, lane = tid & 63;
    int wr = wave >> 1, wc = wave & 1;      // 2 x 2 wave grid, 64x64 per wave
    int g = lane >> 4, tl = lane & 15;

    // staging (r11/r13-verified involution): lane -> (row = base + lane>>2,
    // slot p = lane&3); source granule = inverse rotation
    int srow = lane >> 2;
    int gsrc = ((lane & 3) - ((lane >> 3) & 3)) & 3;
    const u8* pA0 = Aq + (size_t)(ibase + wave * 32 + srow) * DIM + gsrc * 16;
    const u8* pA1 = Aq + (size_t)(ibase + wave * 32 + 16 + srow) * DIM + gsrc * 16;
    const u8* pB0 = Aq + (size_t)(jbase + wave * 32 + srow) * DIM + gsrc * 16;
    const u8* pB1 = Aq + (size_t)(jbase + wave * 32 + 16 + srow) * DIM + gsrc * 16;

    // ds_read byte offsets: row r slot s at r*64 + s*16, s = (g + ((tl>>1)&3))&3
    int swz = (g + ((tl >> 1) & 3)) & 3;
    int aOff[4], bOff[4];
    #pragma unroll
    for (int mf = 0; mf < 4; ++mf)
        aOff[mf] = (wr * 64 + mf * 16 + tl) * 64 + swz * 16;
    #pragma unroll
    for (int nf = 0; nf < 4; ++nf)
        bOff[nf] = 8192 + (wc * 64 + nf * 16 + tl) * 64 + swz * 16;

    f32x4 acc[4][4];
    f32x4 zero = {0.f, 0.f, 0.f, 0.f};
    #pragma unroll
    for (int mf = 0; mf < 4; ++mf)
        #pragma unroll
        for (int nf = 0; nf < 4; ++nf) acc[mf][nf] = zero;

    auto stage = [&](int t, int slot) {
        u8* base = &lds[slot][0];
        __builtin_amdgcn_global_load_lds((const AS1 void*)(pA0 + t * 64),
            (AS3 void*)(base + wave * 2048), 16, 0, 0);
        __builtin_amdgcn_global_load_lds((const AS1 void*)(pA1 + t * 64),
            (AS3 void*)(base + wave * 2048 + 1024), 16, 0, 0);
        __builtin_amdgcn_global_load_lds((const AS1 void*)(pB0 + t * 64),
            (AS3 void*)(base + 8192 + wave * 2048), 16, 0, 0);
        __builtin_amdgcn_global_load_lds((const AS1 void*)(pB1 + t * 64),
            (AS3 void*)(base + 8192 + wave * 2048 + 1024), 16, 0, 0);
    };

    // prologue: stage slices 0,1; certify slice 0 (slice 1's 4 loads in flight)
    stage(0, 0);
    stage(1, 1);
    asm volatile("s_waitcnt vmcnt(4)" ::: "memory");
    __builtin_amdgcn_s_barrier();
    __builtin_amdgcn_sched_barrier(0);

    #pragma unroll
    for (int t = 0; t < NSLICE; ++t) {
        const int slot = t % RING;
        if (t + 2 < NSLICE) stage(t + 2, (t + 2) % RING);

        const u8* base = &lds[slot][0];
        ulx2 av4[4], bv4[4];
        #pragma unroll
        for (int mf = 0; mf < 4; ++mf)
            av4[mf] = *reinterpret_cast<const ulx2*>(base + aOff[mf]);
        #pragma unroll
        for (int nf = 0; nf < 4; ++nf)
            bv4[nf] = *reinterpret_cast<const ulx2*>(base + bOff[nf]);

        __builtin_amdgcn_s_setprio(1);
        #pragma unroll
        for (int mf = 0; mf < 4; ++mf)
            #pragma unroll
            for (int nf = 0; nf < 4; ++nf)
                acc[mf][nf] = __builtin_amdgcn_mfma_f32_16x16x32_fp8_fp8(
                    (long)av4[mf][0], (long)bv4[nf][0], acc[mf][nf], 0, 0, 0);
        #pragma unroll
        for (int mf = 0; mf < 4; ++mf)
            #pragma unroll
            for (int nf = 0; nf < 4; ++nf)
                acc[mf][nf] = __builtin_amdgcn_mfma_f32_16x16x32_fp8_fp8(
                    (long)av4[mf][1], (long)bv4[nf][1], acc[mf][nf], 0, 0, 0);
        __builtin_amdgcn_s_setprio(0);

        if (t + 1 < NSLICE) {
            if (t + 2 < NSLICE) { asm volatile("s_waitcnt vmcnt(4)" ::: "memory"); }
            else                { asm volatile("s_waitcnt vmcnt(0)" ::: "memory"); }
            __builtin_amdgcn_s_barrier();
            __builtin_amdgcn_sched_barrier(0);
        }
    }

    const float INF = __builtin_inff();

    // ---- row-side: rows I, min over this wave's 64 cols (r11-verified) ----
    // C/D 16x16 layout: col = lane&15, row = (lane>>4)*4 + reg (dtype-independent)
    float bb[4];
    #pragma unroll
    for (int nf = 0; nf < 4; ++nf) bb[nf] = beta[jbase + wc * 64 + nf * 16 + tl];

    #pragma unroll
    for (int mf = 0; mf < 4; ++mf) {
        int grow0 = ibase + wr * 64 + mf * 16 + g * 4;
        float mn0 = INF, mn1 = INF, mn2 = INF, mn3 = INF;
        #pragma unroll
        for (int nf = 0; nf < 4; ++nf) {
            int gcol = jbase + wc * 64 + nf * 16 + tl;
            float c0 = fmaf(-2.f, acc[mf][nf][0], bb[nf]);
            float c1 = fmaf(-2.f, acc[mf][nf][1], bb[nf]);
            float c2 = fmaf(-2.f, acc[mf][nf][2], bb[nf]);
            float c3 = fmaf(-2.f, acc[mf][nf][3], bb[nf]);
            if (grow0 + 0 == gcol) c0 = INF;   // exact-diag only; disjoint if off-diag
            if (grow0 + 1 == gcol) c1 = INF;
            if (grow0 + 2 == gcol) c2 = INF;
            if (grow0 + 3 == gcol) c3 = INF;
            mn0 = fminf(mn0, c0);
            mn1 = fminf(mn1, c1);
            mn2 = fminf(mn2, c2);
            mn3 = fminf(mn3, c3);
        }
        #pragma unroll
        for (int mask = 1; mask < 16; mask <<= 1) {
            mn0 = fminf(mn0, __shfl_xor(mn0, mask, 64));
            mn1 = fminf(mn1, __shfl_xor(mn1, mask, 64));
            mn2 = fminf(mn2, __shfl_xor(mn2, mask, 64));
            mn3 = fminf(mn3, __shfl_xor(mn3, mask, 64));
        }
        if (tl == 0) {
            float d20 = fmaxf(alpha[grow0 + 0] + DEPS2 + mn0, 0.f);
            float d21 = fmaxf(alpha[grow0 + 1] + DEPS2 + mn1, 0.f);
            float d22 = fmaxf(alpha[grow0 + 2] + DEPS2 + mn2, 0.f);
            float d23 = fmaxf(alpha[grow0 + 3] + DEPS2 + mn3, 0.f);
            atomicMin(dan2 + grow0 + 0, __float_as_uint(d20));
            atomicMin(dan2 + grow0 + 1, __float_as_uint(d21));
            atomicMin(dan2 + grow0 + 2, __float_as_uint(d22));
            atomicMin(dan2 + grow0 + 3, __float_as_uint(d23));
        }
    }

    // ---- col-side (off-diag only): this wave's 64 cols, min over its 64 rows ----
    if (!diag) {
        #pragma unroll
        for (int nf = 0; nf < 4; ++nf) {
            int gcol = jbase + wc * 64 + nf * 16 + tl;
            float cm = INF;
            #pragma unroll
            for (int mf = 0; mf < 4; ++mf) {
                int grow0 = ibase + wr * 64 + mf * 16 + g * 4;
                #pragma unroll
                for (int e = 0; e < 4; ++e) {
                    float c = fmaf(-2.f, acc[mf][nf][e], beta[grow0 + e]);
                    cm = fminf(cm, c);
                }
            }
            cm = fminf(cm, __shfl_xor(cm, 16, 64));
            cm = fminf(cm, __shfl_xor(cm, 32, 64));
            if (g == 0) {
                float d2 = fmaxf(alpha[gcol] + DEPS2 + cm, 0.f);
                atomicMin(dan2 + gcol, __float_as_uint(d2));
            }
        }
    }

    // ---- fused finalize: last block to finish reduces the loss ----
    __shared__ unsigned int lastv;
    __shared__ float red[4];
    __threadfence();                      // make our atomicMins visible first
    if (tid == 0) lastv = atomicAdd(cnt, 1u);
    __syncthreads();
    if (lastv == NTILES - 1) {            // block-uniform condition
        __threadfence();                  // acquire: see all blocks' dan2 updates
        float sum = 0.f;
        for (int i = tid; i < N; i += 256) {
            float dan = sqrtf(__uint_as_float(dan2[i]));
            sum += fmaxf(dap[i] - dan + MARGIN, 0.f);
        }
        #pragma unroll
        for (int mask = 32; mask; mask >>= 1) sum += __shfl_xor(sum, mask, 64);
        if (lane == 0) red[wave] = sum;
        __syncthreads();
        if (tid == 0) out[0] = (red[0] + red[1] + red[2] + red[3]) / (float)N;
    }
}

extern "C" void kernel_launch(void* const* d_in, const int* in_sizes, int n_in,
                              void* d_out, int out_size, void* d_ws, size_t ws_size,
                              hipStream_t stream) {
    const float* anchor   = (const float*)d_in[0];
    const float* positive = (const float*)d_in[1];
    int N = in_sizes[0] / DIM;   // 8192
    float* out = (float*)d_out;

    char* ws = (char*)d_ws;
    float* alpha = (float*)ws;
    float* beta  = alpha + N;
    float* dap   = beta + N;
    unsigned int* dan2 = (unsigned int*)(dap + N);
    unsigned int* cnt  = dan2 + N;
    u8* Aq = (u8*)(cnt + 64);   // N*DIM fp8 = 4.2 MB, k-permuted layout

    prep_kernel<<<N / 4, 256, 0, stream>>>(anchor, positive, Aq, alpha, beta, dap, dan2, cnt, N);
    // triangular 128^2 tiles: 64*65/2 = 2080 = 8*260
    gemm_min_kernel<<<NTILES, 256, 0, stream>>>(Aq, alpha, beta, dan2, dap, cnt, out, N);
}

// Round 15
// 58.189 us; speedup vs baseline: 3.2733x; 3.2733x over previous
//
#include <hip/hip_runtime.h>

typedef unsigned char u8;
typedef float f32x4 __attribute__((ext_vector_type(4)));
typedef unsigned long ulx2 __attribute__((ext_vector_type(2)));
typedef unsigned int uix2 __attribute__((ext_vector_type(2)));

#define DIM 512
#define EPSV 1e-6f
#define MARGIN 0.2f
#define DEPS2 (512.0f * 1e-6f * 1e-6f)
#define BK 64
#define NSLICE (DIM / BK)   // 8
#define RING 3

#define AS1 __attribute__((address_space(1)))
#define AS3 __attribute__((address_space(3)))

// ---------------- Kernel 1: per-row stats + fp8 e4m3 convert (k-permuted) ----------------
// Layout per row (512 B): k-block kb (64 elems), granule j (16 B) at byte
// kb*64 + j*16 = fp8[kb*64 + j*8 ..+7] (lo 8B) || fp8[kb*64 + 32 + j*8 ..+7] (hi 8B)
// -- one b128 LDS read yields BOTH K=32 MFMA frags (r13-verified).
__global__ __launch_bounds__(256) void prep_kernel(
        const float* __restrict__ A, const float* __restrict__ P,
        u8* __restrict__ Aq, float* __restrict__ alpha,
        float* __restrict__ beta, float* __restrict__ dap,
        unsigned int* __restrict__ dan2, int N) {
    int row = blockIdx.x * 4 + (threadIdx.x >> 6);
    int lane = threadIdx.x & 63;
    if (row >= N) return;
    const float* a = A + (size_t)row * DIM + lane * 8;
    const float* p = P + (size_t)row * DIM + lane * 8;
    float4 a0 = *(const float4*)(a);
    float4 a1 = *(const float4*)(a + 4);
    float4 p0 = *(const float4*)(p);
    float4 p1 = *(const float4*)(p + 4);
    float av[8] = {a0.x, a0.y, a0.z, a0.w, a1.x, a1.y, a1.z, a1.w};
    float pv[8] = {p0.x, p0.y, p0.z, p0.w, p1.x, p1.y, p1.z, p1.w};
    float sq = 0.f, s = 0.f, dp = 0.f;
    #pragma unroll
    for (int e = 0; e < 8; ++e) {
        float x = av[e];
        sq = fmaf(x, x, sq);
        s += x;
        float d = x - pv[e] + EPSV;
        dp = fmaf(d, d, dp);
    }
    unsigned w0 = __builtin_amdgcn_cvt_pk_fp8_f32(av[0], av[1], 0, false);
    w0 = __builtin_amdgcn_cvt_pk_fp8_f32(av[2], av[3], w0, true);
    unsigned w1 = __builtin_amdgcn_cvt_pk_fp8_f32(av[4], av[5], 0, false);
    w1 = __builtin_amdgcn_cvt_pk_fp8_f32(av[6], av[7], w1, true);
    int kb = lane >> 3, c = lane & 7;
    int dst = kb * 64 + (c & 3) * 16 + (c >> 2) * 8;
    uix2 w = {w0, w1};
    *reinterpret_cast<uix2*>(Aq + (size_t)row * DIM + dst) = w;

    #pragma unroll
    for (int mask = 32; mask; mask >>= 1) {
        sq += __shfl_xor(sq, mask, 64);
        s  += __shfl_xor(s,  mask, 64);
        dp += __shfl_xor(dp, mask, 64);
    }
    if (lane == 0) {
        alpha[row] = fmaf(2.0f * EPSV, s, sq);
        beta[row]  = fmaf(-2.0f * EPSV, s, sq);
        dap[row]   = sqrtf(dp);
        dan2[row]  = 0x7f800000u;   // +inf
    }
}

// ---------------- Kernel 2: 256x128-tile ring-3 fp8 Gram + row/col min ----------------
// r13-verified chassis (45.8 us, absmax 0.0, 0 conflicts). One micro-reorder:
// the 8 critical-path ds_reads issue BEFORE the 3 non-critical stage VMEM ops
// (stage data is needed 2 slices later; reads feed this slice's MFMAs).
__global__ __launch_bounds__(512, 4) void gemm_min_kernel(
        const u8* __restrict__ Aq, const float* __restrict__ alpha,
        const float* __restrict__ beta, unsigned int* __restrict__ dan2, int N) {

    __shared__ u8 lds[RING][24576];   // 72 KiB: per slot A=16384 B, B=8192 B

    // XCD-chunked bijective swizzle: 1056 = 8 * 132
    int orig = blockIdx.x;
    int v = (orig & 7) * 132 + (orig >> 3);

    // decode v -> (a, btile): offset(a) = a*(65-a), btile = 2a + (v - offset(a))
    int a = (int)((65.0f - sqrtf(4225.0f - 4.0f * (float)v)) * 0.5f);
    while ((a + 1) * (65 - (a + 1)) <= v) ++a;
    while (a * (65 - a) > v) --a;
    int btile = 2 * a + (v - a * (65 - a));
    int ibase = a << 8, jbase = btile << 7;

    int tid = threadIdx.x;
    int wave = tid >> 6, lane = tid & 63;
    int wr = wave >> 1, wc = wave & 1;      // 4 x 2 wave grid, 64x64 per wave
    int g = lane >> 4, tl = lane & 15;

    // staging (verified involution): lane -> (row = base + lane>>2, slot p = lane&3);
    // source granule = inverse rotation
    int srow = lane >> 2;
    int gsrc = ((lane & 3) - ((lane >> 3) & 3)) & 3;
    const u8* pA0 = Aq + (size_t)(ibase + wave * 32 + srow) * DIM + gsrc * 16;
    const u8* pA1 = Aq + (size_t)(ibase + wave * 32 + 16 + srow) * DIM + gsrc * 16;
    const u8* pB  = Aq + (size_t)(jbase + wave * 16 + srow) * DIM + gsrc * 16;

    // ds_read byte offsets: row r slot s at r*64 + s*16, s = (g + ((tl>>1)&3))&3
    int swz = (g + ((tl >> 1) & 3)) & 3;
    int aOff[4], bOff[4];
    #pragma unroll
    for (int mf = 0; mf < 4; ++mf)
        aOff[mf] = (wr * 64 + mf * 16 + tl) * 64 + swz * 16;
    #pragma unroll
    for (int nf = 0; nf < 4; ++nf)
        bOff[nf] = 16384 + (wc * 64 + nf * 16 + tl) * 64 + swz * 16;

    f32x4 acc[4][4];
    f32x4 zero = {0.f, 0.f, 0.f, 0.f};
    #pragma unroll
    for (int mf = 0; mf < 4; ++mf)
        #pragma unroll
        for (int nf = 0; nf < 4; ++nf) acc[mf][nf] = zero;

    auto stage = [&](int t, int slot) {
        u8* base = &lds[slot][0];
        __builtin_amdgcn_global_load_lds((const AS1 void*)(pA0 + t * 64),
            (AS3 void*)(base + wave * 2048), 16, 0, 0);
        __builtin_amdgcn_global_load_lds((const AS1 void*)(pA1 + t * 64),
            (AS3 void*)(base + wave * 2048 + 1024), 16, 0, 0);
        __builtin_amdgcn_global_load_lds((const AS1 void*)(pB + t * 64),
            (AS3 void*)(base + 16384 + wave * 1024), 16, 0, 0);
    };

    // prologue: stage slices 0,1; certify slice 0 (slice 1's 3 loads in flight)
    stage(0, 0);
    stage(1, 1);
    asm volatile("s_waitcnt vmcnt(3)" ::: "memory");
    __builtin_amdgcn_s_barrier();
    __builtin_amdgcn_sched_barrier(0);

    #pragma unroll
    for (int t = 0; t < NSLICE; ++t) {
        const int slot = t % RING;

        // critical-path ds_reads first
        const u8* base = &lds[slot][0];
        ulx2 av4[4], bv4[4];
        #pragma unroll
        for (int mf = 0; mf < 4; ++mf)
            av4[mf] = *reinterpret_cast<const ulx2*>(base + aOff[mf]);
        #pragma unroll
        for (int nf = 0; nf < 4; ++nf)
            bv4[nf] = *reinterpret_cast<const ulx2*>(base + bOff[nf]);

        // non-critical prefetch staging after
        if (t + 2 < NSLICE) stage(t + 2, (t + 2) % RING);

        __builtin_amdgcn_s_setprio(1);
        #pragma unroll
        for (int mf = 0; mf < 4; ++mf)
            #pragma unroll
            for (int nf = 0; nf < 4; ++nf)
                acc[mf][nf] = __builtin_amdgcn_mfma_f32_16x16x32_fp8_fp8(
                    (long)av4[mf][0], (long)bv4[nf][0], acc[mf][nf], 0, 0, 0);
        #pragma unroll
        for (int mf = 0; mf < 4; ++mf)
            #pragma unroll
            for (int nf = 0; nf < 4; ++nf)
                acc[mf][nf] = __builtin_amdgcn_mfma_f32_16x16x32_fp8_fp8(
                    (long)av4[mf][1], (long)bv4[nf][1], acc[mf][nf], 0, 0, 0);
        __builtin_amdgcn_s_setprio(0);

        if (t + 1 < NSLICE) {
            if (t + 2 < NSLICE) { asm volatile("s_waitcnt vmcnt(3)" ::: "memory"); }
            else                { asm volatile("s_waitcnt vmcnt(0)" ::: "memory"); }
            __builtin_amdgcn_s_barrier();
            __builtin_amdgcn_sched_barrier(0);
        }
    }

    const float INF = __builtin_inff();

    // ---- row-side: rows I, min over this wave's 64 cols (verified) ----
    // C/D 16x16 layout: col = lane&15, row = (lane>>4)*4 + reg (dtype-independent)
    float bb[4];
    #pragma unroll
    for (int nf = 0; nf < 4; ++nf) bb[nf] = beta[jbase + wc * 64 + nf * 16 + tl];

    #pragma unroll
    for (int mf = 0; mf < 4; ++mf) {
        int grow0 = ibase + wr * 64 + mf * 16 + g * 4;
        float mn0 = INF, mn1 = INF, mn2 = INF, mn3 = INF;
        #pragma unroll
        for (int nf = 0; nf < 4; ++nf) {
            int gcol = jbase + wc * 64 + nf * 16 + tl;
            float c0 = fmaf(-2.f, acc[mf][nf][0], bb[nf]);
            float c1 = fmaf(-2.f, acc[mf][nf][1], bb[nf]);
            float c2 = fmaf(-2.f, acc[mf][nf][2], bb[nf]);
            float c3 = fmaf(-2.f, acc[mf][nf][3], bb[nf]);
            if (grow0 + 0 == gcol) c0 = INF;
            if (grow0 + 1 == gcol) c1 = INF;
            if (grow0 + 2 == gcol) c2 = INF;
            if (grow0 + 3 == gcol) c3 = INF;
            mn0 = fminf(mn0, c0);
            mn1 = fminf(mn1, c1);
            mn2 = fminf(mn2, c2);
            mn3 = fminf(mn3, c3);
        }
        #pragma unroll
        for (int mask = 1; mask < 16; mask <<= 1) {
            mn0 = fminf(mn0, __shfl_xor(mn0, mask, 64));
            mn1 = fminf(mn1, __shfl_xor(mn1, mask, 64));
            mn2 = fminf(mn2, __shfl_xor(mn2, mask, 64));
            mn3 = fminf(mn3, __shfl_xor(mn3, mask, 64));
        }
        if (tl == 0) {
            float d20 = fmaxf(alpha[grow0 + 0] + DEPS2 + mn0, 0.f);
            float d21 = fmaxf(alpha[grow0 + 1] + DEPS2 + mn1, 0.f);
            float d22 = fmaxf(alpha[grow0 + 2] + DEPS2 + mn2, 0.f);
            float d23 = fmaxf(alpha[grow0 + 3] + DEPS2 + mn3, 0.f);
            atomicMin(dan2 + grow0 + 0, __float_as_uint(d20));
            atomicMin(dan2 + grow0 + 1, __float_as_uint(d21));
            atomicMin(dan2 + grow0 + 2, __float_as_uint(d22));
            atomicMin(dan2 + grow0 + 3, __float_as_uint(d23));
        }
    }

    // ---- col-side: this wave's 64 cols, min over the wave's 64 rows (diag masked) ----
    #pragma unroll
    for (int nf = 0; nf < 4; ++nf) {
        int gcol = jbase + wc * 64 + nf * 16 + tl;
        float cm = INF;
        #pragma unroll
        for (int mf = 0; mf < 4; ++mf) {
            int grow0 = ibase + wr * 64 + mf * 16 + g * 4;
            #pragma unroll
            for (int e = 0; e < 4; ++e) {
                int rowg = grow0 + e;
                float c = fmaf(-2.f, acc[mf][nf][e], beta[rowg]);
                if (rowg == gcol) c = INF;
                cm = fminf(cm, c);
            }
        }
        cm = fminf(cm, __shfl_xor(cm, 16, 64));
        cm = fminf(cm, __shfl_xor(cm, 32, 64));
        if (g == 0) {
            float d2 = fmaxf(alpha[gcol] + DEPS2 + cm, 0.f);
            atomicMin(dan2 + gcol, __float_as_uint(d2));
        }
    }
}

// ---------------- Kernel 3: final loss reduction ----------------
__global__ __launch_bounds__(1024) void finalize_kernel(
        const float* __restrict__ dap, const unsigned int* __restrict__ dan2,
        float* __restrict__ out, int N) {
    __shared__ float red[16];
    float sum = 0.f;
    for (int i = threadIdx.x; i < N; i += 1024) {
        float dan = sqrtf(__uint_as_float(dan2[i]));
        float v = dap[i] - dan + MARGIN;
        sum += fmaxf(v, 0.f);
    }
    #pragma unroll
    for (int mask = 32; mask; mask >>= 1) sum += __shfl_xor(sum, mask, 64);
    int lane = threadIdx.x & 63, w = threadIdx.x >> 6;
    if (lane == 0) red[w] = sum;
    __syncthreads();
    if (threadIdx.x == 0) {
        float tot = 0.f;
        #pragma unroll
        for (int k = 0; k < 16; ++k) tot += red[k];
        out[0] = tot / (float)N;
    }
}

extern "C" void kernel_launch(void* const* d_in, const int* in_sizes, int n_in,
                              void* d_out, int out_size, void* d_ws, size_t ws_size,
                              hipStream_t stream) {
    const float* anchor   = (const float*)d_in[0];
    const float* positive = (const float*)d_in[1];
    int N = in_sizes[0] / DIM;   // 8192
    float* out = (float*)d_out;

    char* ws = (char*)d_ws;
    float* alpha = (float*)ws;
    float* beta  = alpha + N;
    float* dap   = beta + N;
    unsigned int* dan2 = (unsigned int*)(dap + N);
    u8* Aq = (u8*)(dan2 + N);   // N*DIM fp8 = 4.2 MB, k-permuted layout

    prep_kernel<<<N / 4, 256, 0, stream>>>(anchor, positive, Aq, alpha, beta, dap, dan2, N);
    // kept tiles: (a, b) with b >= 2a; count = sum_a (64-2a) = 1056 = 8*132
    gemm_min_kernel<<<1056, 512, 0, stream>>>(Aq, alpha, beta, dan2, N);
    finalize_kernel<<<1, 1024, 0, stream>>>(dap, dan2, out, N);
}